// Round 1
// baseline (230.722 us; speedup 1.0000x reference)
//
#include <hip/hip_runtime.h>
#include <stdint.h>

// Problem dims (fixed by reference)
#define BDIM  4096
#define NIN   1024
#define NHID  4096
#define NOUT  1024

typedef unsigned short u16;
typedef unsigned int   u32;
typedef __attribute__((ext_vector_type(8))) __bf16 bf16x8;
typedef __attribute__((ext_vector_type(4))) float  f32x4;

__device__ __forceinline__ u16 f32_to_bf16_rne(float f) {
    u32 u = __builtin_bit_cast(u32, f);
    u = (u + 0x7fffu + ((u >> 16) & 1u)) >> 16;
    return (u16)u;
}

// ---------------- pre-pass: cast x (fp32 -> bf16, same layout) --------------
__global__ void cast_f32_bf16(const float* __restrict__ in, u16* __restrict__ out, int n4) {
    int i = blockIdx.x * blockDim.x + threadIdx.x;
    if (i >= n4) return;
    float4 v = ((const float4*)in)[i];
    ushort4 o;
    o.x = f32_to_bf16_rne(v.x);
    o.y = f32_to_bf16_rne(v.y);
    o.z = f32_to_bf16_rne(v.z);
    o.w = f32_to_bf16_rne(v.w);
    ((ushort4*)out)[i] = o;
}

// ---------------- pre-pass: transpose + cast: in[R][C] f32 -> out[C][R] bf16
__global__ void transpose_cast(const float* __restrict__ in, u16* __restrict__ out,
                               int R, int C) {
    __shared__ float tile[32][33];
    const int rt = blockIdx.y * 32;   // row base in 'in'
    const int ct = blockIdx.x * 32;   // col base in 'in'
    const int tid = threadIdx.x;      // 256 threads
    const int c  = tid & 31;
    const int r4 = tid >> 5;          // 0..7
#pragma unroll
    for (int rr = 0; rr < 4; ++rr) {
        int r = r4 * 4 + rr;
        tile[r][c] = in[(size_t)(rt + r) * C + (ct + c)];
    }
    __syncthreads();
#pragma unroll
    for (int rr = 0; rr < 4; ++rr) {
        int r = r4 * 4 + rr;          // output row within tile == original col
        out[(size_t)(ct + r) * R + (rt + c)] = f32_to_bf16_rne(tile[c][r]);
    }
}

// ---------------- GEMM: C[M][N] = A[M][K] * Bt[N][K]^T, bias epilogue -------
// EPI==0: out = bf16 relu(acc + bias);  EPI==1: out = f32 (acc + bias)
template<int BN, int EPI>
__global__ __launch_bounds__(256) void gemm_bt(
    const u16* __restrict__ A, const u16* __restrict__ Bt,
    const float* __restrict__ bias, void* __restrict__ outp,
    int M, int N, int K)
{
    constexpr int BM = 128;
    constexpr int MI = 4;          // 64 rows per wave / 16
    constexpr int NI = BN / 32;    // (BN/2) cols per wave / 16
    __shared__ __align__(16) u16 smemA[BM * 32];
    __shared__ __align__(16) u16 smemB[BN * 32];

    const int tid  = threadIdx.x;
    const int lane = tid & 63;
    const int wave = tid >> 6;
    const int rowBase = blockIdx.y * BM;
    const int colBase = blockIdx.x * BN;
    const int wrow = (wave >> 1) * 64;
    const int wcol = (wave & 1) * (BN / 2);

    f32x4 acc[MI][NI] = {};

    const int srow  = lane >> 2;        // row within 16-row staging region
    const int sbyte = (lane & 3) * 16;  // byte chunk within 64B row
    constexpr int RA = BM / 64;         // A staging issues per wave
    constexpr int RB = BN / 64;         // B staging issues per wave

    for (int k0 = 0; k0 < K; k0 += 32) {
        __syncthreads();   // previous tile fully consumed before overwrite
#pragma unroll
        for (int t = 0; t < RA; ++t) {
            int region = wave * RA + t;                 // 16-row / 1024B region
            int arow = rowBase + region * 16 + srow;
            const u16* g = A + (size_t)arow * K + k0 + (sbyte >> 1);
            __builtin_amdgcn_global_load_lds(
                (const __attribute__((address_space(1))) u32*)g,
                (__attribute__((address_space(3))) u32*)(smemA + region * 512),
                16, 0, 0);
        }
#pragma unroll
        for (int t = 0; t < RB; ++t) {
            int region = wave * RB + t;
            int brow = colBase + region * 16 + srow;
            const u16* g = Bt + (size_t)brow * K + k0 + (sbyte >> 1);
            __builtin_amdgcn_global_load_lds(
                (const __attribute__((address_space(1))) u32*)g,
                (__attribute__((address_space(3))) u32*)(smemB + region * 512),
                16, 0, 0);
        }
        __builtin_amdgcn_s_waitcnt(0);
        __syncthreads();   // staged tile visible to all waves

        const char* aBase = (const char*)smemA +
            ((wrow + (lane & 15)) * 64 + (lane >> 4) * 16);
        const char* bBase = (const char*)smemB +
            ((wcol + (lane & 15)) * 64 + (lane >> 4) * 16);
        bf16x8 af[MI], bfv[NI];
#pragma unroll
        for (int mi = 0; mi < MI; ++mi)
            af[mi] = *(const bf16x8*)(aBase + mi * 16 * 64);
#pragma unroll
        for (int ni = 0; ni < NI; ++ni)
            bfv[ni] = *(const bf16x8*)(bBase + ni * 16 * 64);
#pragma unroll
        for (int mi = 0; mi < MI; ++mi)
#pragma unroll
            for (int ni = 0; ni < NI; ++ni)
                acc[mi][ni] = __builtin_amdgcn_mfma_f32_16x16x32_bf16(
                    af[mi], bfv[ni], acc[mi][ni], 0, 0, 0);
    }

    // Epilogue. C/D layout: col = lane&15, row = (lane>>4)*4 + reg  [m89/m91]
    const int col0 = colBase + wcol + (lane & 15);
    const int row0 = rowBase + wrow + ((lane >> 4) << 2);
#pragma unroll
    for (int ni = 0; ni < NI; ++ni) {
        const int col = col0 + ni * 16;
        const float bv = bias[col];
#pragma unroll
        for (int mi = 0; mi < MI; ++mi) {
            const int row = row0 + mi * 16;
#pragma unroll
            for (int r = 0; r < 4; ++r) {
                float v = acc[mi][ni][r] + bv;
                if (EPI == 0) {
                    v = v > 0.f ? v : 0.f;
                    ((u16*)outp)[(size_t)(row + r) * N + col] = f32_to_bf16_rne(v);
                } else {
                    ((float*)outp)[(size_t)(row + r) * N + col] = v;
                }
            }
        }
    }
}

extern "C" void kernel_launch(void* const* d_in, const int* in_sizes, int n_in,
                              void* d_out, int out_size, void* d_ws, size_t ws_size,
                              hipStream_t stream) {
    const float* x  = (const float*)d_in[0];
    const float* W1 = (const float*)d_in[1];
    const float* b1 = (const float*)d_in[2];
    const float* W2 = (const float*)d_in[3];
    const float* b2 = (const float*)d_in[4];

    char* ws = (char*)d_ws;
    const size_t MB = 1024 * 1024;
    u16* x_bf = (u16*)(ws + 0 * MB);    //  8 MB : x bf16 [4096][1024]
    u16* W1t  = (u16*)(ws + 8 * MB);    //  8 MB : W1^T bf16 [4096][1024]
    u16* W2t  = (u16*)(ws + 16 * MB);   //  8 MB : W2^T bf16 [1024][4096]
    u16* h_bf = (u16*)(ws + 24 * MB);   // 32 MB : h bf16 [4096][4096]

    // pre-pass
    int n4 = BDIM * NIN / 4;
    cast_f32_bf16<<<(n4 + 255) / 256, 256, 0, stream>>>(x, x_bf, n4);
    transpose_cast<<<dim3(NHID / 32, NIN / 32), 256, 0, stream>>>(W1, W1t, NIN, NHID);
    transpose_cast<<<dim3(NOUT / 32, NHID / 32), 256, 0, stream>>>(W2, W2t, NHID, NOUT);

    // h = relu(x @ W1 + b1)   [M=4096, N=4096, K=1024]
    gemm_bt<128, 0><<<dim3(NHID / 128, BDIM / 128), 256, 0, stream>>>(
        x_bf, W1t, b1, h_bf, BDIM, NHID, NIN);

    // y = h @ W2 + b2         [M=4096, N=1024, K=4096]
    gemm_bt<64, 1><<<dim3(NOUT / 64, BDIM / 128), 256, 0, stream>>>(
        h_bf, W2t, b2, d_out, BDIM, NOUT, NHID);
}

// Round 2
// 228.474 us; speedup vs baseline: 1.0098x; 1.0098x over previous
//
#include <hip/hip_runtime.h>
#include <stdint.h>

// Problem dims (fixed by reference)
#define BDIM  4096
#define NIN   1024
#define NHID  4096
#define NOUT  1024

typedef unsigned short u16;
typedef unsigned int   u32;
typedef __attribute__((ext_vector_type(8))) __bf16 bf16x8;
typedef __attribute__((ext_vector_type(4))) float  f32x4;

__device__ __forceinline__ u16 f32_to_bf16_rne(float f) {
    u32 u = __builtin_bit_cast(u32, f);
    u = (u + 0x7fffu + ((u >> 16) & 1u)) >> 16;
    return (u16)u;
}

// ---------------- pre-pass: cast x (fp32 -> bf16, same layout) --------------
__global__ void cast_f32_bf16(const float* __restrict__ in, u16* __restrict__ out, int n4) {
    int i = blockIdx.x * blockDim.x + threadIdx.x;
    if (i >= n4) return;
    float4 v = ((const float4*)in)[i];
    ushort4 o;
    o.x = f32_to_bf16_rne(v.x);
    o.y = f32_to_bf16_rne(v.y);
    o.z = f32_to_bf16_rne(v.z);
    o.w = f32_to_bf16_rne(v.w);
    ((ushort4*)out)[i] = o;
}

// ---------------- pre-pass: transpose + cast: in[R][C] f32 -> out[C][R] bf16
__global__ void transpose_cast(const float* __restrict__ in, u16* __restrict__ out,
                               int R, int C) {
    __shared__ float tile[32][33];
    const int rt = blockIdx.y * 32;   // row base in 'in'
    const int ct = blockIdx.x * 32;   // col base in 'in'
    const int tid = threadIdx.x;      // 256 threads
    const int c  = tid & 31;
    const int r4 = tid >> 5;          // 0..7
#pragma unroll
    for (int rr = 0; rr < 4; ++rr) {
        int r = r4 * 4 + rr;
        tile[r][c] = in[(size_t)(rt + r) * C + (ct + c)];
    }
    __syncthreads();
#pragma unroll
    for (int rr = 0; rr < 4; ++rr) {
        int r = r4 * 4 + rr;          // output row within tile == original col
        out[(size_t)(ct + r) * R + (rt + c)] = f32_to_bf16_rne(tile[c][r]);
    }
}

// ---------------- GEMM1: C[M][N] = A[M][K]*Bt[N][K]^T, bf16 relu(acc+bias) --
__global__ __launch_bounds__(256) void gemm_bt_relu(
    const u16* __restrict__ A, const u16* __restrict__ Bt,
    const float* __restrict__ bias, u16* __restrict__ outp,
    int M, int N, int K)
{
    constexpr int BM = 128, BN = 128, MI = 4, NI = 4;
    __shared__ __align__(16) u16 smemA[BM * 32];
    __shared__ __align__(16) u16 smemB[BN * 32];

    const int tid  = threadIdx.x;
    const int lane = tid & 63;
    const int wave = tid >> 6;
    const int rowBase = blockIdx.y * BM;
    const int colBase = blockIdx.x * BN;
    const int wrow = (wave >> 1) * 64;
    const int wcol = (wave & 1) * 64;

    f32x4 acc[MI][NI] = {};

    const int srow  = lane >> 2;
    const int sbyte = (lane & 3) * 16;

    for (int k0 = 0; k0 < K; k0 += 32) {
        __syncthreads();
#pragma unroll
        for (int t = 0; t < 2; ++t) {
            int region = wave * 2 + t;
            int arow = rowBase + region * 16 + srow;
            const u16* g = A + (size_t)arow * K + k0 + (sbyte >> 1);
            __builtin_amdgcn_global_load_lds(
                (const __attribute__((address_space(1))) u32*)g,
                (__attribute__((address_space(3))) u32*)(smemA + region * 512),
                16, 0, 0);
        }
#pragma unroll
        for (int t = 0; t < 2; ++t) {
            int region = wave * 2 + t;
            int brow = colBase + region * 16 + srow;
            const u16* g = Bt + (size_t)brow * K + k0 + (sbyte >> 1);
            __builtin_amdgcn_global_load_lds(
                (const __attribute__((address_space(1))) u32*)g,
                (__attribute__((address_space(3))) u32*)(smemB + region * 512),
                16, 0, 0);
        }
        __builtin_amdgcn_s_waitcnt(0);
        __syncthreads();

        const char* aBase = (const char*)smemA +
            ((wrow + (lane & 15)) * 64 + (lane >> 4) * 16);
        const char* bBase = (const char*)smemB +
            ((wcol + (lane & 15)) * 64 + (lane >> 4) * 16);
        bf16x8 af[MI], bfv[NI];
#pragma unroll
        for (int mi = 0; mi < MI; ++mi)
            af[mi] = *(const bf16x8*)(aBase + mi * 16 * 64);
#pragma unroll
        for (int ni = 0; ni < NI; ++ni)
            bfv[ni] = *(const bf16x8*)(bBase + ni * 16 * 64);
#pragma unroll
        for (int mi = 0; mi < MI; ++mi)
#pragma unroll
            for (int ni = 0; ni < NI; ++ni)
                acc[mi][ni] = __builtin_amdgcn_mfma_f32_16x16x32_bf16(
                    af[mi], bfv[ni], acc[mi][ni], 0, 0, 0);
    }

    const int col0 = colBase + wcol + (lane & 15);
    const int row0 = rowBase + wrow + ((lane >> 4) << 2);
#pragma unroll
    for (int ni = 0; ni < NI; ++ni) {
        const int col = col0 + ni * 16;
        const float bv = bias[col];
#pragma unroll
        for (int mi = 0; mi < MI; ++mi) {
            const int row = row0 + mi * 16;
#pragma unroll
            for (int r = 0; r < 4; ++r) {
                float v = acc[mi][ni][r] + bv;
                v = v > 0.f ? v : 0.f;
                outp[(size_t)(row + r) * N + col] = f32_to_bf16_rne(v);
            }
        }
    }
}

// ---------------- GEMM2 (split-K): raw fp32 partials, no bias ---------------
// blockIdx.z = split index; z==0 -> out0 (d_out), z>0 -> pextra[(z-1)*M*N]
__global__ __launch_bounds__(256) void gemm_bt_splitk(
    const u16* __restrict__ A, const u16* __restrict__ Bt,
    float* __restrict__ out0, float* __restrict__ pextra,
    int M, int N, int K, int Kchunk)
{
    constexpr int BM = 128, BN = 128, MI = 4, NI = 4;
    __shared__ __align__(16) u16 smemA[BM * 32];
    __shared__ __align__(16) u16 smemB[BN * 32];

    const int tid  = threadIdx.x;
    const int lane = tid & 63;
    const int wave = tid >> 6;
    const int rowBase = blockIdx.y * BM;
    const int colBase = blockIdx.x * BN;
    const int z = blockIdx.z;
    const int kBeg = z * Kchunk;
    const int kEnd = kBeg + Kchunk;
    const int wrow = (wave >> 1) * 64;
    const int wcol = (wave & 1) * 64;

    f32x4 acc[MI][NI] = {};

    const int srow  = lane >> 2;
    const int sbyte = (lane & 3) * 16;

    for (int k0 = kBeg; k0 < kEnd; k0 += 32) {
        __syncthreads();
#pragma unroll
        for (int t = 0; t < 2; ++t) {
            int region = wave * 2 + t;
            int arow = rowBase + region * 16 + srow;
            const u16* g = A + (size_t)arow * K + k0 + (sbyte >> 1);
            __builtin_amdgcn_global_load_lds(
                (const __attribute__((address_space(1))) u32*)g,
                (__attribute__((address_space(3))) u32*)(smemA + region * 512),
                16, 0, 0);
        }
#pragma unroll
        for (int t = 0; t < 2; ++t) {
            int region = wave * 2 + t;
            int brow = colBase + region * 16 + srow;
            const u16* g = Bt + (size_t)brow * K + k0 + (sbyte >> 1);
            __builtin_amdgcn_global_load_lds(
                (const __attribute__((address_space(1))) u32*)g,
                (__attribute__((address_space(3))) u32*)(smemB + region * 512),
                16, 0, 0);
        }
        __builtin_amdgcn_s_waitcnt(0);
        __syncthreads();

        const char* aBase = (const char*)smemA +
            ((wrow + (lane & 15)) * 64 + (lane >> 4) * 16);
        const char* bBase = (const char*)smemB +
            ((wcol + (lane & 15)) * 64 + (lane >> 4) * 16);
        bf16x8 af[MI], bfv[NI];
#pragma unroll
        for (int mi = 0; mi < MI; ++mi)
            af[mi] = *(const bf16x8*)(aBase + mi * 16 * 64);
#pragma unroll
        for (int ni = 0; ni < NI; ++ni)
            bfv[ni] = *(const bf16x8*)(bBase + ni * 16 * 64);
#pragma unroll
        for (int mi = 0; mi < MI; ++mi)
#pragma unroll
            for (int ni = 0; ni < NI; ++ni)
                acc[mi][ni] = __builtin_amdgcn_mfma_f32_16x16x32_bf16(
                    af[mi], bfv[ni], acc[mi][ni], 0, 0, 0);
    }

    float* outp = (z == 0) ? out0 : (pextra + (size_t)(z - 1) * M * N);
    const int col0 = colBase + wcol + (lane & 15);
    const int row0 = rowBase + wrow + ((lane >> 4) << 2);
#pragma unroll
    for (int ni = 0; ni < NI; ++ni) {
        const int col = col0 + ni * 16;
#pragma unroll
        for (int mi = 0; mi < MI; ++mi) {
            const int row = row0 + mi * 16;
#pragma unroll
            for (int r = 0; r < 4; ++r)
                outp[(size_t)(row + r) * N + col] = acc[mi][ni][r];
        }
    }
}

// ---------------- split-K reduce: out0 += sum(partials) + bias --------------
template<int SM1>   // number of extra partials (S-1)
__global__ void splitk_reduce(float* __restrict__ out0,
                              const float* __restrict__ pextra,
                              const float* __restrict__ bias,
                              int n4, int nCols4) {
    int i = blockIdx.x * blockDim.x + threadIdx.x;
    if (i >= n4) return;
    float4 v = ((const float4*)out0)[i];
    const size_t stride4 = (size_t)n4;
#pragma unroll
    for (int s = 0; s < SM1; ++s) {
        float4 p = ((const float4*)pextra)[i + s * stride4];
        v.x += p.x; v.y += p.y; v.z += p.z; v.w += p.w;
    }
    float4 bv = ((const float4*)bias)[i & (nCols4 - 1)];
    v.x += bv.x; v.y += bv.y; v.z += bv.z; v.w += bv.w;
    ((float4*)out0)[i] = v;
}

extern "C" void kernel_launch(void* const* d_in, const int* in_sizes, int n_in,
                              void* d_out, int out_size, void* d_ws, size_t ws_size,
                              hipStream_t stream) {
    const float* x  = (const float*)d_in[0];
    const float* W1 = (const float*)d_in[1];
    const float* b1 = (const float*)d_in[2];
    const float* W2 = (const float*)d_in[3];
    const float* b2 = (const float*)d_in[4];

    char* ws = (char*)d_ws;
    const size_t MB = 1024 * 1024;
    // layout: W2t @0 (8MB), h @8 (32MB), x_bf @40 (8MB), W1t @48 (8MB),
    //         split-K extra partials @56 (16MB each, up to 3)
    u16* W2t  = (u16*)(ws + 0 * MB);
    u16* h_bf = (u16*)(ws + 8 * MB);
    u16* x_bf = (u16*)(ws + 40 * MB);
    u16* W1t  = (u16*)(ws + 48 * MB);

    const int S = (ws_size >= 104 * MB) ? 4 : 2;
    // S==4: 3 extra partials at 56MB. S==2: 1 extra partial reusing the
    // x_bf/W1t region (dead after gemm1) at 40MB.
    float* pextra = (S == 4) ? (float*)(ws + 56 * MB) : (float*)(ws + 40 * MB);

    // pre-pass
    int n4 = BDIM * NIN / 4;
    cast_f32_bf16<<<(n4 + 255) / 256, 256, 0, stream>>>(x, x_bf, n4);
    transpose_cast<<<dim3(NHID / 32, NIN / 32), 256, 0, stream>>>(W1, W1t, NIN, NHID);
    transpose_cast<<<dim3(NOUT / 32, NHID / 32), 256, 0, stream>>>(W2, W2t, NHID, NOUT);

    // h = relu(x @ W1 + b1)   [M=4096, N=4096, K=1024]
    gemm_bt_relu<<<dim3(NHID / 128, BDIM / 128), 256, 0, stream>>>(
        x_bf, W1t, b1, h_bf, BDIM, NHID, NIN);

    // y = h @ W2 + b2         [M=4096, N=1024, K=4096], split-K
    gemm_bt_splitk<<<dim3(NOUT / 128, BDIM / 128, S), 256, 0, stream>>>(
        h_bf, W2t, (float*)d_out, pextra, BDIM, NOUT, NHID, NHID / S);

    int rn4 = BDIM * NOUT / 4;
    if (S == 4)
        splitk_reduce<3><<<(rn4 + 255) / 256, 256, 0, stream>>>(
            (float*)d_out, pextra, b2, rn4, NOUT / 4);
    else
        splitk_reduce<1><<<(rn4 + 255) / 256, 256, 0, stream>>>(
            (float*)d_out, pextra, b2, rn4, NOUT / 4);
}

// Round 3
// 220.200 us; speedup vs baseline: 1.0478x; 1.0376x over previous
//
#include <hip/hip_runtime.h>
#include <stdint.h>

// Problem dims (fixed by reference)
#define BDIM  4096
#define NIN   1024
#define NHID  4096
#define NOUT  1024

typedef unsigned short u16;
typedef unsigned int   u32;
typedef __attribute__((ext_vector_type(8))) __bf16 bf16x8;
typedef __attribute__((ext_vector_type(4))) float  f32x4;

__device__ __forceinline__ u16 f32_to_bf16_rne(float f) {
    u32 u = __builtin_bit_cast(u32, f);
    u = (u + 0x7fffu + ((u >> 16) & 1u)) >> 16;
    return (u16)u;
}

// ---------------- pre-pass: cast x (fp32 -> bf16, same layout) --------------
__global__ void cast_f32_bf16(const float* __restrict__ in, u16* __restrict__ out, int n4) {
    int i = blockIdx.x * blockDim.x + threadIdx.x;
    if (i >= n4) return;
    float4 v = ((const float4*)in)[i];
    ushort4 o;
    o.x = f32_to_bf16_rne(v.x);
    o.y = f32_to_bf16_rne(v.y);
    o.z = f32_to_bf16_rne(v.z);
    o.w = f32_to_bf16_rne(v.w);
    ((ushort4*)out)[i] = o;
}

// ---------------- pre-pass: transpose + cast: in[R][C] f32 -> out[C][R] bf16
__global__ void transpose_cast(const float* __restrict__ in, u16* __restrict__ out,
                               int R, int C) {
    __shared__ float tile[32][33];
    const int rt = blockIdx.y * 32;   // row base in 'in'
    const int ct = blockIdx.x * 32;   // col base in 'in'
    const int tid = threadIdx.x;      // 256 threads
    const int c  = tid & 31;
    const int r4 = tid >> 5;          // 0..7
#pragma unroll
    for (int rr = 0; rr < 4; ++rr) {
        int r = r4 * 4 + rr;
        tile[r][c] = in[(size_t)(rt + r) * C + (ct + c)];
    }
    __syncthreads();
#pragma unroll
    for (int rr = 0; rr < 4; ++rr) {
        int r = r4 * 4 + rr;          // output row within tile == original col
        out[(size_t)(ct + r) * R + (rt + c)] = f32_to_bf16_rne(tile[c][r]);
    }
}

// ---------------- GEMM1: C[M][N] = A[M][K]*Bt[N][K]^T, bf16 relu(acc+bias) --
__global__ __launch_bounds__(256) void gemm_bt_relu(
    const u16* __restrict__ A, const u16* __restrict__ Bt,
    const float* __restrict__ bias, u16* __restrict__ outp,
    int M, int N, int K)
{
    constexpr int BM = 128, BN = 128, MI = 4, NI = 4;
    __shared__ __align__(16) u16 smemA[BM * 32];
    __shared__ __align__(16) u16 smemB[BN * 32];

    const int tid  = threadIdx.x;
    const int lane = tid & 63;
    const int wave = tid >> 6;
    const int rowBase = blockIdx.y * BM;
    const int colBase = blockIdx.x * BN;
    const int wrow = (wave >> 1) * 64;
    const int wcol = (wave & 1) * 64;

    f32x4 acc[MI][NI] = {};

    const int srow  = lane >> 2;
    const int sbyte = (lane & 3) * 16;

    for (int k0 = 0; k0 < K; k0 += 32) {
        __syncthreads();
#pragma unroll
        for (int t = 0; t < 2; ++t) {
            int region = wave * 2 + t;
            int arow = rowBase + region * 16 + srow;
            const u16* g = A + (size_t)arow * K + k0 + (sbyte >> 1);
            __builtin_amdgcn_global_load_lds(
                (const __attribute__((address_space(1))) u32*)g,
                (__attribute__((address_space(3))) u32*)(smemA + region * 512),
                16, 0, 0);
        }
#pragma unroll
        for (int t = 0; t < 2; ++t) {
            int region = wave * 2 + t;
            int brow = colBase + region * 16 + srow;
            const u16* g = Bt + (size_t)brow * K + k0 + (sbyte >> 1);
            __builtin_amdgcn_global_load_lds(
                (const __attribute__((address_space(1))) u32*)g,
                (__attribute__((address_space(3))) u32*)(smemB + region * 512),
                16, 0, 0);
        }
        __builtin_amdgcn_s_waitcnt(0);
        __syncthreads();

        const char* aBase = (const char*)smemA +
            ((wrow + (lane & 15)) * 64 + (lane >> 4) * 16);
        const char* bBase = (const char*)smemB +
            ((wcol + (lane & 15)) * 64 + (lane >> 4) * 16);
        bf16x8 af[MI], bfv[NI];
#pragma unroll
        for (int mi = 0; mi < MI; ++mi)
            af[mi] = *(const bf16x8*)(aBase + mi * 16 * 64);
#pragma unroll
        for (int ni = 0; ni < NI; ++ni)
            bfv[ni] = *(const bf16x8*)(bBase + ni * 16 * 64);
#pragma unroll
        for (int mi = 0; mi < MI; ++mi)
#pragma unroll
            for (int ni = 0; ni < NI; ++ni)
                acc[mi][ni] = __builtin_amdgcn_mfma_f32_16x16x32_bf16(
                    af[mi], bfv[ni], acc[mi][ni], 0, 0, 0);
    }

    const int col0 = colBase + wcol + (lane & 15);
    const int row0 = rowBase + wrow + ((lane >> 4) << 2);
#pragma unroll
    for (int ni = 0; ni < NI; ++ni) {
        const int col = col0 + ni * 16;
        const float bv = bias[col];
#pragma unroll
        for (int mi = 0; mi < MI; ++mi) {
            const int row = row0 + mi * 16;
#pragma unroll
            for (int r = 0; r < 4; ++r) {
                float v = acc[mi][ni][r] + bv;
                v = v > 0.f ? v : 0.f;
                outp[(size_t)(row + r) * N + col] = f32_to_bf16_rne(v);
            }
        }
    }
}

// ---------------- GEMM2 (split-K, S=2): raw fp32 partials, no bias ----------
// blockIdx.z = split index; z==0 -> out0 (d_out), z==1 -> pextra
__global__ __launch_bounds__(256) void gemm_bt_splitk(
    const u16* __restrict__ A, const u16* __restrict__ Bt,
    float* __restrict__ out0, float* __restrict__ pextra,
    int M, int N, int K, int Kchunk)
{
    constexpr int BM = 128, BN = 128, MI = 4, NI = 4;
    __shared__ __align__(16) u16 smemA[BM * 32];
    __shared__ __align__(16) u16 smemB[BN * 32];

    const int tid  = threadIdx.x;
    const int lane = tid & 63;
    const int wave = tid >> 6;
    const int rowBase = blockIdx.y * BM;
    const int colBase = blockIdx.x * BN;
    const int z = blockIdx.z;
    const int kBeg = z * Kchunk;
    const int kEnd = kBeg + Kchunk;
    const int wrow = (wave >> 1) * 64;
    const int wcol = (wave & 1) * 64;

    f32x4 acc[MI][NI] = {};

    const int srow  = lane >> 2;
    const int sbyte = (lane & 3) * 16;

    for (int k0 = kBeg; k0 < kEnd; k0 += 32) {
        __syncthreads();
#pragma unroll
        for (int t = 0; t < 2; ++t) {
            int region = wave * 2 + t;
            int arow = rowBase + region * 16 + srow;
            const u16* g = A + (size_t)arow * K + k0 + (sbyte >> 1);
            __builtin_amdgcn_global_load_lds(
                (const __attribute__((address_space(1))) u32*)g,
                (__attribute__((address_space(3))) u32*)(smemA + region * 512),
                16, 0, 0);
        }
#pragma unroll
        for (int t = 0; t < 2; ++t) {
            int region = wave * 2 + t;
            int brow = colBase + region * 16 + srow;
            const u16* g = Bt + (size_t)brow * K + k0 + (sbyte >> 1);
            __builtin_amdgcn_global_load_lds(
                (const __attribute__((address_space(1))) u32*)g,
                (__attribute__((address_space(3))) u32*)(smemB + region * 512),
                16, 0, 0);
        }
        __builtin_amdgcn_s_waitcnt(0);
        __syncthreads();

        const char* aBase = (const char*)smemA +
            ((wrow + (lane & 15)) * 64 + (lane >> 4) * 16);
        const char* bBase = (const char*)smemB +
            ((wcol + (lane & 15)) * 64 + (lane >> 4) * 16);
        bf16x8 af[MI], bfv[NI];
#pragma unroll
        for (int mi = 0; mi < MI; ++mi)
            af[mi] = *(const bf16x8*)(aBase + mi * 16 * 64);
#pragma unroll
        for (int ni = 0; ni < NI; ++ni)
            bfv[ni] = *(const bf16x8*)(bBase + ni * 16 * 64);
#pragma unroll
        for (int mi = 0; mi < MI; ++mi)
#pragma unroll
            for (int ni = 0; ni < NI; ++ni)
                acc[mi][ni] = __builtin_amdgcn_mfma_f32_16x16x32_bf16(
                    af[mi], bfv[ni], acc[mi][ni], 0, 0, 0);
    }

    float* outp = (z == 0) ? out0 : pextra;
    const int col0 = colBase + wcol + (lane & 15);
    const int row0 = rowBase + wrow + ((lane >> 4) << 2);
#pragma unroll
    for (int ni = 0; ni < NI; ++ni) {
        const int col = col0 + ni * 16;
#pragma unroll
        for (int mi = 0; mi < MI; ++mi) {
            const int row = row0 + mi * 16;
#pragma unroll
            for (int r = 0; r < 4; ++r)
                outp[(size_t)(row + r) * N + col] = acc[mi][ni][r];
        }
    }
}

// ---------------- split-K reduce: out0 = out0 + p + bias --------------------
__global__ void splitk_reduce(float* __restrict__ out0,
                              const float* __restrict__ p,
                              const float* __restrict__ bias,
                              int n4, int nCols4) {
    int i = blockIdx.x * blockDim.x + threadIdx.x;
    if (i >= n4) return;
    float4 v = ((const float4*)out0)[i];
    float4 q = ((const float4*)p)[i];
    float4 bv = ((const float4*)bias)[i & (nCols4 - 1)];
    v.x += q.x + bv.x; v.y += q.y + bv.y;
    v.z += q.z + bv.z; v.w += q.w + bv.w;
    ((float4*)out0)[i] = v;
}

extern "C" void kernel_launch(void* const* d_in, const int* in_sizes, int n_in,
                              void* d_out, int out_size, void* d_ws, size_t ws_size,
                              hipStream_t stream) {
    const float* x  = (const float*)d_in[0];
    const float* W1 = (const float*)d_in[1];
    const float* b1 = (const float*)d_in[2];
    const float* W2 = (const float*)d_in[3];
    const float* b2 = (const float*)d_in[4];

    char* ws = (char*)d_ws;
    const size_t MB = 1024 * 1024;
    // layout: W2t @0 (8MB), h @8 (32MB), x_bf @40 (8MB), W1t @48 (8MB),
    //         split-K extra partial @56 (16MB)
    u16*   W2t  = (u16*)(ws + 0 * MB);
    u16*   h_bf = (u16*)(ws + 8 * MB);
    u16*   x_bf = (u16*)(ws + 40 * MB);
    u16*   W1t  = (u16*)(ws + 48 * MB);
    float* p1   = (float*)(ws + 56 * MB);

    // pre-pass
    int n4 = BDIM * NIN / 4;
    cast_f32_bf16<<<(n4 + 255) / 256, 256, 0, stream>>>(x, x_bf, n4);
    transpose_cast<<<dim3(NHID / 32, NIN / 32), 256, 0, stream>>>(W1, W1t, NIN, NHID);
    transpose_cast<<<dim3(NOUT / 32, NHID / 32), 256, 0, stream>>>(W2, W2t, NHID, NOUT);

    // h = relu(x @ W1 + b1)   [M=4096, N=4096, K=1024]
    gemm_bt_relu<<<dim3(NHID / 128, BDIM / 128), 256, 0, stream>>>(
        x_bf, W1t, b1, h_bf, BDIM, NHID, NIN);

    // y = h @ W2 + b2         [M=4096, N=1024, K=4096], split-K S=2
    gemm_bt_splitk<<<dim3(NOUT / 128, BDIM / 128, 2), 256, 0, stream>>>(
        h_bf, W2t, (float*)d_out, p1, BDIM, NOUT, NHID, NHID / 2);

    int rn4 = BDIM * NOUT / 4;
    splitk_reduce<<<(rn4 + 255) / 256, 256, 0, stream>>>(
        (float*)d_out, p1, b2, rn4, NOUT / 4);
}

// Round 4
// 194.636 us; speedup vs baseline: 1.1854x; 1.1313x over previous
//
#include <hip/hip_runtime.h>
#include <stdint.h>

// Problem dims (fixed by reference)
#define BDIM  4096
#define NIN   1024
#define NHID  4096
#define NOUT  1024

typedef unsigned short u16;
typedef unsigned int   u32;
typedef __attribute__((ext_vector_type(8))) __bf16 bf16x8;
typedef __attribute__((ext_vector_type(4))) float  f32x4;

__device__ __forceinline__ u16 f32_to_bf16_rne(float f) {
    u32 u = __builtin_bit_cast(u32, f);
    u = (u + 0x7fffu + ((u >> 16) & 1u)) >> 16;
    return (u16)u;
}

// ------------- fused pre-pass: cast x + transpose W1 + transpose W2 ---------
// blocks [0,4096): cast x chunk; [4096,8192): W1 tile; [8192,12288): W2 tile
__device__ __forceinline__ void transpose_tile(
    const float* __restrict__ in, u16* __restrict__ out,
    int R, int C, int bx, int by, float (*tile)[33]) {
    const int rt = by * 32, ct = bx * 32;
    const int tid = threadIdx.x;
    const int c  = tid & 31;
    const int r4 = tid >> 5;
#pragma unroll
    for (int rr = 0; rr < 4; ++rr) {
        int r = r4 * 4 + rr;
        tile[r][c] = in[(size_t)(rt + r) * C + (ct + c)];
    }
    __syncthreads();
#pragma unroll
    for (int rr = 0; rr < 4; ++rr) {
        int r = r4 * 4 + rr;
        out[(size_t)(ct + r) * R + (rt + c)] = f32_to_bf16_rne(tile[c][r]);
    }
}

__global__ void prepass(const float* __restrict__ x,  u16* __restrict__ x_bf,
                        const float* __restrict__ W1, u16* __restrict__ W1t,
                        const float* __restrict__ W2, u16* __restrict__ W2t) {
    __shared__ float tile[32][33];
    const int b = blockIdx.x;
    if (b < 4096) {
        int i = b * 256 + threadIdx.x;          // 1M float4 total
        float4 v = ((const float4*)x)[i];
        ushort4 o;
        o.x = f32_to_bf16_rne(v.x); o.y = f32_to_bf16_rne(v.y);
        o.z = f32_to_bf16_rne(v.z); o.w = f32_to_bf16_rne(v.w);
        ((ushort4*)x_bf)[i] = o;
    } else if (b < 8192) {
        int t = b - 4096;                       // W1: R=1024, C=4096
        transpose_tile(W1, W1t, NIN, NHID, t & 127, t >> 7, tile);
    } else {
        int t = b - 8192;                       // W2: R=4096, C=1024
        transpose_tile(W2, W2t, NHID, NOUT, t & 31, t >> 5, tile);
    }
}

// ---------------- GEMM core: BK=64, xor-swizzled LDS, 128x128 tile ----------
// Stages A[128][64] and Bt[128][64] per iteration. LDS row = 128B (8 chunks of
// 16B); chunk c of row r lives at physical slot c^(r&7)  -> conflict-free
// ds_read_b128 across the 16 fragment rows. The swizzle is applied on the
// GLOBAL fetch side (lane fetches chunk (lane&7)^(lane>>3) of its row), since
// global_load_lds pins LDS addr to base+lane*16.
template<int EPI>   // 0: bf16 relu(acc+bias) out; 1: raw f32 partial out
__global__ __launch_bounds__(256) void gemm_bt(
    const u16* __restrict__ A, const u16* __restrict__ Bt,
    const float* __restrict__ bias, void* __restrict__ outp,
    int M, int N, int K, int kBeg, int kEnd)
{
    constexpr int MI = 4, NI = 4;
    __shared__ __align__(16) u16 smemA[128 * 64];
    __shared__ __align__(16) u16 smemB[128 * 64];

    const int tid  = threadIdx.x;
    const int lane = tid & 63;
    const int wave = tid >> 6;
    const int rowBase = blockIdx.y * 128;
    const int colBase = blockIdx.x * 128;
    const int wrow = (wave >> 1) * 64;
    const int wcol = (wave & 1) * 64;

    f32x4 acc[MI][NI] = {};

    const int srow    = lane >> 3;                    // 0..7 row in region
    const int chunkSw = (lane & 7) ^ srow;            // swizzled global chunk
    const int gcol    = chunkSw * 8;                  // elem offset in row

    const int fr = lane & 15;
    const int fq = lane >> 4;
    const int sw = fr & 7;

    for (int k0 = kBeg; k0 < kEnd; k0 += 64) {
        __syncthreads();
#pragma unroll
        for (int t = 0; t < 4; ++t) {
            int region = wave * 4 + t;                // 8-row / 1KB region
            int arow = rowBase + region * 8 + srow;
            const u16* g = A + (size_t)arow * K + k0 + gcol;
            __builtin_amdgcn_global_load_lds(
                (const __attribute__((address_space(1))) u32*)g,
                (__attribute__((address_space(3))) u32*)(smemA + region * 512),
                16, 0, 0);
        }
#pragma unroll
        for (int t = 0; t < 4; ++t) {
            int region = wave * 4 + t;
            int brow = colBase + region * 8 + srow;
            const u16* g = Bt + (size_t)brow * K + k0 + gcol;
            __builtin_amdgcn_global_load_lds(
                (const __attribute__((address_space(1))) u32*)g,
                (__attribute__((address_space(3))) u32*)(smemB + region * 512),
                16, 0, 0);
        }
        __builtin_amdgcn_s_waitcnt(0);
        __syncthreads();

#pragma unroll
        for (int s = 0; s < 2; ++s) {
            const int co = ((s * 4 + fq) ^ sw) * 16;  // physical chunk byte
            const char* aB = (const char*)smemA + (wrow + fr) * 128 + co;
            const char* bB = (const char*)smemB + (wcol + fr) * 128 + co;
            bf16x8 af[MI], bfv[NI];
#pragma unroll
            for (int mi = 0; mi < MI; ++mi)
                af[mi] = *(const bf16x8*)(aB + mi * 2048);
#pragma unroll
            for (int ni = 0; ni < NI; ++ni)
                bfv[ni] = *(const bf16x8*)(bB + ni * 2048);
#pragma unroll
            for (int mi = 0; mi < MI; ++mi)
#pragma unroll
                for (int ni = 0; ni < NI; ++ni)
                    acc[mi][ni] = __builtin_amdgcn_mfma_f32_16x16x32_bf16(
                        af[mi], bfv[ni], acc[mi][ni], 0, 0, 0);
        }
    }

    // C/D layout: col = lane&15, row = (lane>>4)*4 + reg  [m89/m91]
    const int col0 = colBase + wcol + fr;
    const int row0 = rowBase + wrow + (fq << 2);
#pragma unroll
    for (int ni = 0; ni < NI; ++ni) {
        const int col = col0 + ni * 16;
        const float bv = (EPI == 0) ? bias[col] : 0.f;
#pragma unroll
        for (int mi = 0; mi < MI; ++mi) {
            const int row = row0 + mi * 16;
#pragma unroll
            for (int r = 0; r < 4; ++r) {
                if (EPI == 0) {
                    float v = acc[mi][ni][r] + bv;
                    v = v > 0.f ? v : 0.f;
                    ((u16*)outp)[(size_t)(row + r) * N + col] = f32_to_bf16_rne(v);
                } else {
                    ((float*)outp)[(size_t)(row + r) * N + col] = acc[mi][ni][r];
                }
            }
        }
    }
}

// split-K z-dispatch wrapper for GEMM2 (z==0 -> out0, z==1 -> p1)
__global__ __launch_bounds__(256) void gemm_bt_splitk(
    const u16* __restrict__ A, const u16* __restrict__ Bt,
    float* __restrict__ out0, float* __restrict__ p1,
    int M, int N, int K, int Kchunk);

// Implement splitk by re-entering the template body via a thin kernel: easier
// to just duplicate the launch with kBeg/kEnd and two output pointers.

// ---------------- split-K reduce: out0 = out0 + p + bias --------------------
__global__ void splitk_reduce(float* __restrict__ out0,
                              const float* __restrict__ p,
                              const float* __restrict__ bias,
                              int n4, int nCols4) {
    int i = blockIdx.x * blockDim.x + threadIdx.x;
    if (i >= n4) return;
    float4 v = ((const float4*)out0)[i];
    float4 q = ((const float4*)p)[i];
    float4 bv = ((const float4*)bias)[i & (nCols4 - 1)];
    v.x += q.x + bv.x; v.y += q.y + bv.y;
    v.z += q.z + bv.z; v.w += q.w + bv.w;
    ((float4*)out0)[i] = v;
}

// GEMM2 with split-K folded in via blockIdx.z (avoids two separate launches)
__global__ __launch_bounds__(256) void gemm2_splitk(
    const u16* __restrict__ A, const u16* __restrict__ Bt,
    float* __restrict__ out0, float* __restrict__ p1,
    int M, int N, int K, int Kchunk)
{
    constexpr int MI = 4, NI = 4;
    __shared__ __align__(16) u16 smemA[128 * 64];
    __shared__ __align__(16) u16 smemB[128 * 64];

    const int tid  = threadIdx.x;
    const int lane = tid & 63;
    const int wave = tid >> 6;
    const int rowBase = blockIdx.y * 128;
    const int colBase = blockIdx.x * 128;
    const int z    = blockIdx.z;
    const int kBeg = z * Kchunk;
    const int kEnd = kBeg + Kchunk;
    const int wrow = (wave >> 1) * 64;
    const int wcol = (wave & 1) * 64;

    f32x4 acc[MI][NI] = {};

    const int srow    = lane >> 3;
    const int chunkSw = (lane & 7) ^ srow;
    const int gcol    = chunkSw * 8;
    const int fr = lane & 15;
    const int fq = lane >> 4;
    const int sw = fr & 7;

    for (int k0 = kBeg; k0 < kEnd; k0 += 64) {
        __syncthreads();
#pragma unroll
        for (int t = 0; t < 4; ++t) {
            int region = wave * 4 + t;
            int arow = rowBase + region * 8 + srow;
            const u16* g = A + (size_t)arow * K + k0 + gcol;
            __builtin_amdgcn_global_load_lds(
                (const __attribute__((address_space(1))) u32*)g,
                (__attribute__((address_space(3))) u32*)(smemA + region * 512),
                16, 0, 0);
        }
#pragma unroll
        for (int t = 0; t < 4; ++t) {
            int region = wave * 4 + t;
            int brow = colBase + region * 8 + srow;
            const u16* g = Bt + (size_t)brow * K + k0 + gcol;
            __builtin_amdgcn_global_load_lds(
                (const __attribute__((address_space(1))) u32*)g,
                (__attribute__((address_space(3))) u32*)(smemB + region * 512),
                16, 0, 0);
        }
        __builtin_amdgcn_s_waitcnt(0);
        __syncthreads();

#pragma unroll
        for (int s = 0; s < 2; ++s) {
            const int co = ((s * 4 + fq) ^ sw) * 16;
            const char* aB = (const char*)smemA + (wrow + fr) * 128 + co;
            const char* bB = (const char*)smemB + (wcol + fr) * 128 + co;
            bf16x8 af[MI], bfv[NI];
#pragma unroll
            for (int mi = 0; mi < MI; ++mi)
                af[mi] = *(const bf16x8*)(aB + mi * 2048);
#pragma unroll
            for (int ni = 0; ni < NI; ++ni)
                bfv[ni] = *(const bf16x8*)(bB + ni * 2048);
#pragma unroll
            for (int mi = 0; mi < MI; ++mi)
#pragma unroll
                for (int ni = 0; ni < NI; ++ni)
                    acc[mi][ni] = __builtin_amdgcn_mfma_f32_16x16x32_bf16(
                        af[mi], bfv[ni], acc[mi][ni], 0, 0, 0);
        }
    }

    float* outp = (z == 0) ? out0 : p1;
    const int col0 = colBase + wcol + fr;
    const int row0 = rowBase + wrow + (fq << 2);
#pragma unroll
    for (int ni = 0; ni < NI; ++ni) {
        const int col = col0 + ni * 16;
#pragma unroll
        for (int mi = 0; mi < MI; ++mi) {
            const int row = row0 + mi * 16;
#pragma unroll
            for (int r = 0; r < 4; ++r)
                outp[(size_t)(row + r) * N + col] = acc[mi][ni][r];
        }
    }
}

extern "C" void kernel_launch(void* const* d_in, const int* in_sizes, int n_in,
                              void* d_out, int out_size, void* d_ws, size_t ws_size,
                              hipStream_t stream) {
    const float* x  = (const float*)d_in[0];
    const float* W1 = (const float*)d_in[1];
    const float* b1 = (const float*)d_in[2];
    const float* W2 = (const float*)d_in[3];
    const float* b2 = (const float*)d_in[4];

    char* ws = (char*)d_ws;
    const size_t MB = 1024 * 1024;
    u16*   W2t  = (u16*)(ws + 0 * MB);    //  8 MB
    u16*   h_bf = (u16*)(ws + 8 * MB);    // 32 MB
    u16*   x_bf = (u16*)(ws + 40 * MB);   //  8 MB
    u16*   W1t  = (u16*)(ws + 48 * MB);   //  8 MB
    float* p1   = (float*)(ws + 56 * MB); // 16 MB

    // fused pre-pass: cast x + transpose W1 + transpose W2
    prepass<<<12288, 256, 0, stream>>>(x, x_bf, W1, W1t, W2, W2t);

    // h = relu(x @ W1 + b1)   [M=4096, N=4096, K=1024]
    gemm_bt<0><<<dim3(NHID / 128, BDIM / 128), 256, 0, stream>>>(
        x_bf, W1t, b1, h_bf, BDIM, NHID, NIN, 0, NIN);

    // y = h @ W2 + b2         [M=4096, N=1024, K=4096], split-K S=2
    gemm2_splitk<<<dim3(NOUT / 128, BDIM / 128, 2), 256, 0, stream>>>(
        h_bf, W2t, (float*)d_out, p1, BDIM, NOUT, NHID, NHID / 2);

    int rn4 = BDIM * NOUT / 4;
    splitk_reduce<<<(rn4 + 255) / 256, 256, 0, stream>>>(
        (float*)d_out, p1, b2, rn4, NOUT / 4);
}